// Round 13
// baseline (126.350 us; speedup 1.0000x reference)
//
#include <hip/hip_runtime.h>

// DigitCaps dynamic routing — ONE 1024-thread block per (batch, c-half):
// 16 waves = 4 waves/SIMD on each CU, the first occupancy doubling since r7.
// Why this works where r3/r6/r10 failed:
//   - r3/r6: 512-thr blocks clamp VGPR to 128 and the old map needed 170.
//     The o-split map (r7/r12) needs ~116 -> fits the HARD 1024-thr limit
//     (16 waves/CU -> 2048/16 = 128 VGPR).
//   - r10: >256 blocks broke co-residency -> spin serialization. Grid here
//     stays 256 = 1 block/CU; all partners resident; spin-safe.
// Carried verbatim from r12 (absmax 3.8e-6): c-split (16 ch/block), Wm half
// in LDS (80KB), fence-free 2-way ticket sync (relaxed agent atomics, no
// __threadfence), defer-max softmax, 3-phase routing.
// Thread maps rescaled to 1024: A = 16c x 64slot; heavy = 16c x 32slot x 2oh
// (4.5 hw/thr); s-compute = 4-way c-split (640 thr, 4-iter loops).
// Sentinel: if WRITE_SIZE blows up, the compiler clamped VGPR < 116 -> 768thr.

#define BB 128
#define CC 32
#define CL 16     // channels per block
#define HWN 144   // 12*12
#define QQ 8      // IN_CAPS
#define OO 10     // OUT_CH
#define PP 16     // OUT_CAPS
#define OH 5      // o's per lane-half

__device__ float    g_sx[3 * BB * 2 * OO * PP];  // [ph][b][ch][160]
__device__ unsigned g_cnt[BB * 32];              // per-batch tickets, 128B stride

__device__ __forceinline__ float squash16(float s) {
    // tid = o*16 + p : reduce s^2 over the 16 p-lanes (masks 1..8)
    float sn = s * s;
#pragma unroll
    for (int m = 1; m <= 8; m <<= 1) sn += __shfl_xor(sn, m);
    return s * (sqrtf(sn) / (1.f + sn));
}

__global__ __launch_bounds__(1024, 1)
void digitcaps_routing(const float* __restrict__ x, const float* __restrict__ Wm,
                       float* __restrict__ out) {
    const int b   = blockIdx.x;   // 0..127
    const int ch  = blockIdx.y;   // 0..1 c-half
    const int tid = threadIdx.x;  // 0..1023

    __shared__ float Wm_s[CL * OO * PP * QQ];   // 80 KB  (own Wm half)
    __shared__ float usum_s[CL * QQ];           // 512 B
    __shared__ float Wv_s[CL * OO * QQ];        // 5 KB   (logit-weight acc)
    __shared__ float t_s[CL * OO * QQ];         // 5 KB
    __shared__ float v_s[OO * PP];              // 640 B
    __shared__ float ps4_s[4 * OO * PP];        // 2.5 KB (c-quarter partials)

    // ---- stage own Wm half into LDS (5120 float4 = 1024 thr x 5) ----
    {
        const float4* src = (const float4*)(Wm + (size_t)ch * (CL * OO * PP * QQ));
        float4* dst = (float4*)Wm_s;
#pragma unroll
        for (int k = 0; k < 5; ++k) dst[tid + (k << 10)] = src[tid + (k << 10)];
    }

    // ---- A: usum[cl][q] = sum_hw x[b, ch*16+cl, hw, q]  (16c x 64slot) ----
    {
        const int c = tid >> 6, slot = tid & 63;
        const float* xc = x + ((size_t)b * CC + ch * CL + c) * (HWN * QQ);
        float us[QQ];
#pragma unroll
        for (int q = 0; q < QQ; ++q) us[q] = 0.f;
#pragma unroll
        for (int i = 0; i < 3; ++i) {              // 144 = 64*2.25
            const int hw = slot + (i << 6);
            if (hw < HWN) {
                const float4* p4 = (const float4*)(xc + hw * QQ);
                float4 a = p4[0], d = p4[1];
                us[0] += a.x; us[1] += a.y; us[2] += a.z; us[3] += a.w;
                us[4] += d.x; us[5] += d.y; us[6] += d.z; us[7] += d.w;
            }
        }
#pragma unroll
        for (int m = 1; m <= 32; m <<= 1) {        // reduce over 64 slot lanes
#pragma unroll
            for (int q = 0; q < QQ; ++q) us[q] += __shfl_xor(us[q], m);
        }
        if (slot == 0) {
#pragma unroll
            for (int q = 0; q < QQ; ++q) usum_s[c * QQ + q] = us[q];
        }
    }
    __syncthreads();

    // heavy-phase thread map: 16 c x 32 slots x 2 oh
    const int hc    = tid >> 6;          // 0..15 local c
    const int hslot = (tid >> 1) & 31;   // 0..31
    const int oh    = tid & 1;           // 0..1
    const int obase = oh * OH;
    const float* xhc = x + ((size_t)b * CC + ch * CL + hc) * (HWN * QQ);

    // ---- 3 phases: ph=0 -> v1 seed; ph=1,2 -> routing iters ----
    for (int ph = 0; ph < 3; ++ph) {
        // partial s[o,p] over own 16 c, split into 4 x 4-c quarters (640 thr)
        if (tid < 4 * OO * PP) {
            const int h   = tid / (OO * PP);       // 0..3 c quarter
            const int idx = tid - h * (OO * PP);
            const int o = idx >> 4, p = idx & 15;
            const int c0 = h * 4;
            float s = 0.f;
#pragma unroll
            for (int k = 0; k < 4; ++k) {
                const int cc = c0 + k;
                const float4* w4 = (const float4*)(Wm_s + (((cc * OO + o) * PP + p) * QQ));
                float4 w0 = w4[0], w1 = w4[1];
                const float* src = (ph == 0) ? &usum_s[cc * QQ]
                                             : &t_s[(cc * OO + o) * QQ];
                s += w0.x * src[0] + w0.y * src[1] + w0.z * src[2] + w0.w * src[3]
                   + w1.x * src[4] + w1.y * src[5] + w1.z * src[6] + w1.w * src[7];
            }
            ps4_s[tid] = s;
        }
        __syncthreads();

        // ---- exchange 160-float s-partial with the partner block ----
        const int spin = (ph < 2) ? 1 : (ch == 0);
        float sown = 0.f;
        if (tid < OO * PP) {
            sown = (ps4_s[tid] + ps4_s[OO * PP + tid])
                 + (ps4_s[2 * OO * PP + tid] + ps4_s[3 * OO * PP + tid]);
            __hip_atomic_store(&g_sx[(((size_t)ph * BB + b) * 2 + ch) * (OO * PP) + tid],
                               sown, __ATOMIC_RELAXED, __HIP_MEMORY_SCOPE_AGENT);
        }
        __syncthreads();   // drains vmcnt(0): stores at the coherent point
        if (tid == 0) {
            unsigned t = __hip_atomic_fetch_add(&g_cnt[b * 32], 1u,
                             __ATOMIC_RELAXED, __HIP_MEMORY_SCOPE_AGENT);
            if (spin) {
                const unsigned target = (t / 2u + 1u) * 2u;
                while (__hip_atomic_load(&g_cnt[b * 32], __ATOMIC_RELAXED,
                                         __HIP_MEMORY_SCOPE_AGENT) < target)
                    __builtin_amdgcn_s_sleep(1);
            }
        }
        __syncthreads();
        if (!spin) return;   // ch1 at ph==2: posted, done

        // combine partials -> v (or final output)
        if (tid < OO * PP) {
            float soth = __hip_atomic_load(
                &g_sx[(((size_t)ph * BB + b) * 2 + (1 - ch)) * (OO * PP) + tid],
                __ATOMIC_RELAXED, __HIP_MEMORY_SCOPE_AGENT);
            float s = sown + soth;
            if (ph == 0) s *= 0.1f;          // iter-1 uniform c_ij
            const float v = squash16(s);
            if (ph == 2) { out[(size_t)b * (OO * PP) + tid] = v; }
            else         { v_s[tid] = v; }
        }
        if (ph == 2) return;
        __syncthreads();

        // ---- Wv (own c only; set on ph0, accumulate on ph1) ----
        if (tid < CL * OO) {
            const int cl = tid / OO, o = tid - cl * OO;
            float acc[QQ];
#pragma unroll
            for (int q = 0; q < QQ; ++q) acc[q] = 0.f;
            const float* wp = Wm_s + ((cl * OO + o) * PP) * QQ;
#pragma unroll
            for (int p = 0; p < PP; ++p) {
                const float vv = v_s[o * PP + p];
                const float4* w4 = (const float4*)(wp + p * QQ);
                float4 w0 = w4[0], w1 = w4[1];
                acc[0] += vv * w0.x; acc[1] += vv * w0.y; acc[2] += vv * w0.z; acc[3] += vv * w0.w;
                acc[4] += vv * w1.x; acc[5] += vv * w1.y; acc[6] += vv * w1.z; acc[7] += vv * w1.w;
            }
            float* dst = Wv_s + (cl * OO + o) * QQ;
            if (ph == 0) {
#pragma unroll
                for (int q = 0; q < QQ; ++q) dst[q] = acc[q];
            } else {
#pragma unroll
                for (int q = 0; q < QQ; ++q) dst[q] += acc[q];
            }
        }
        __syncthreads();

        // ---- heavy: logits = u.Wv, defer-max softmax, t = sum_hw c_ij*u ----
        float wv[OH][QQ];
#pragma unroll
        for (int j = 0; j < OH; ++j)
#pragma unroll
            for (int q = 0; q < QQ; ++q)
                wv[j][q] = Wv_s[(hc * OO + obase + j) * QQ + q];

        float tl[OH][QQ];
#pragma unroll
        for (int j = 0; j < OH; ++j)
#pragma unroll
            for (int q = 0; q < QQ; ++q) tl[j][q] = 0.f;

#pragma unroll
        for (int i = 0; i < 5; ++i) {        // 144 = 32 slots * 4.5
            const int hw = hslot + (i << 5);
            if (hw < HWN) {
                const float4* p4 = (const float4*)(xhc + hw * QQ);
                float4 a = p4[0], d = p4[1];
                float u[QQ] = {a.x, a.y, a.z, a.w, d.x, d.y, d.z, d.w};
                float lg[OH];
#pragma unroll
                for (int j = 0; j < OH; ++j) {
                    float t = 0.f;
#pragma unroll
                    for (int q = 0; q < QQ; ++q) t += u[q] * wv[j][q];
                    lg[j] = __expf(t);       // defer-max: logits bounded, fp32-safe
                }
                float psum = ((lg[0] + lg[1]) + (lg[2] + lg[3])) + lg[4];
                psum += __shfl_xor(psum, 1);
                const float inv = 1.f / psum;
#pragma unroll
                for (int j = 0; j < OH; ++j) {
                    const float cij = lg[j] * inv;
#pragma unroll
                    for (int q = 0; q < QQ; ++q) tl[j][q] += cij * u[q];
                }
            }
        }
        // reduce t over the 32 slot lanes (masks 2..32; oh is bit0)
#pragma unroll
        for (int m = 2; m <= 32; m <<= 1) {
#pragma unroll
            for (int j = 0; j < OH; ++j)
#pragma unroll
                for (int q = 0; q < QQ; ++q) tl[j][q] += __shfl_xor(tl[j][q], m);
        }
        if (hslot == 0) {
#pragma unroll
            for (int j = 0; j < OH; ++j)
#pragma unroll
                for (int q = 0; q < QQ; ++q)
                    t_s[(hc * OO + obase + j) * QQ + q] = tl[j][q];
        }
        __syncthreads();
    }
}

extern "C" void kernel_launch(void* const* d_in, const int* in_sizes, int n_in,
                              void* d_out, int out_size, void* d_ws, size_t ws_size,
                              hipStream_t stream) {
    const float* x  = (const float*)d_in[0];   // [128,32,12,12,8]
    const float* Wm = (const float*)d_in[1];   // [1,1,32,10,16,8]
    float* out      = (float*)d_out;           // [128,10,16]
    digitcaps_routing<<<dim3(BB, 2), 1024, 0, stream>>>(x, Wm, out);
}

// Round 14
// 90.554 us; speedup vs baseline: 1.3953x; 1.3953x over previous
//
#include <hip/hip_runtime.h>
#include <hip/hip_fp16.h>

// DigitCaps dynamic routing — 2 blocks per batch (c-split, 16 channels each),
// Wm half (80KB, fp32) AND x slice (36.9KB, fp16) staged in LDS.
// r13 lesson: compiler gives one block the whole CU register file
//   (256thr->256, 512thr->128, 1024thr->64 VGPR) -> 1024-thr blocks spill
//   the ~116-reg live set. 512 thr / ~116 VGPR is the operating point.
// r12 base (best, kernel ~39us): c-split + Wm-in-LDS + fence-free 2-way
//   ticket sync (relaxed agent atomics, no __threadfence) + defer-max
//   softmax + o-split heavy map. Carried verbatim.
// This round: absmax threshold is 1.74e-2 and we pass at 1.95e-3 -> stage
//   x-slice as fp16 in LDS. Heavy-phase u loads go L2(~200cy)->LDS(~25cy);
//   staging loads issue alongside Wm staging and hide under the A phase
//   (which still reads global, pre-barrier). LDS total ~131KB -> still
//   1 block/CU -> spin safety unchanged.
// Tickets monotone: 6 increments/batch/launch -> graph-replay safe.

#define BB 128
#define CC 32
#define CL 16     // channels per block
#define HWN 144   // 12*12
#define QQ 8      // IN_CAPS
#define OO 10     // OUT_CH
#define PP 16     // OUT_CAPS
#define OH 5      // o's per lane-half

__device__ float    g_sx[3 * BB * 2 * OO * PP];  // [ph][b][ch][160]
__device__ unsigned g_cnt[BB * 32];              // per-batch tickets, 128B stride

__device__ __forceinline__ float squash16(float s) {
    // tid = o*16 + p : reduce s^2 over the 16 p-lanes (masks 1..8)
    float sn = s * s;
#pragma unroll
    for (int m = 1; m <= 8; m <<= 1) sn += __shfl_xor(sn, m);
    return s * (sqrtf(sn) / (1.f + sn));
}

__global__ __launch_bounds__(512, 1)
void digitcaps_routing(const float* __restrict__ x, const float* __restrict__ Wm,
                       float* __restrict__ out) {
    const int b   = blockIdx.x;   // 0..127
    const int ch  = blockIdx.y;   // 0..1 c-half
    const int tid = threadIdx.x;

    __shared__ float  Wm_s[CL * OO * PP * QQ];   // 80 KB  (own Wm half, fp32)
    __shared__ __half x_s[CL * HWN * QQ];        // 36 KB  (own x slice, fp16)
    __shared__ float  usum_s[CL * QQ];           // 512 B
    __shared__ float  Wv_s[CL * OO * QQ];        // 5 KB   (logit-weight acc)
    __shared__ float  t_s[CL * OO * QQ];         // 5 KB
    __shared__ float  v_s[OO * PP];              // 640 B
    __shared__ float  ps2_s[2 * OO * PP];        // 1.25 KB

    // ---- stage Wm half (5120 float4) + x slice (4608 float4 -> fp16) ----
    {
        const float4* wsrc = (const float4*)(Wm + (size_t)ch * (CL * OO * PP * QQ));
        float4* wdst = (float4*)Wm_s;
#pragma unroll
        for (int k = 0; k < 10; ++k) wdst[tid + (k << 9)] = wsrc[tid + (k << 9)];

        const float4* xsrc = (const float4*)(x + ((size_t)b * CC + ch * CL) * (HWN * QQ));
        __half2* xdst = (__half2*)x_s;
#pragma unroll
        for (int k = 0; k < 9; ++k) {
            const int j = tid + (k << 9);
            float4 v = xsrc[j];
            xdst[2 * j]     = __floats2half2_rn(v.x, v.y);
            xdst[2 * j + 1] = __floats2half2_rn(v.z, v.w);
        }
    }

    // ---- A: usum[cl][q] = sum_hw x[b, ch*16+cl, hw, q]  (global, fp32) ----
    {
        const int c = tid >> 5, slot = tid & 31;   // 16 c x 32 slots
        const float* xc = x + ((size_t)b * CC + ch * CL + c) * (HWN * QQ);
        float us[QQ];
#pragma unroll
        for (int q = 0; q < QQ; ++q) us[q] = 0.f;
#pragma unroll
        for (int i = 0; i < 5; ++i) {              // 144 = 32*4.5
            const int hw = slot + (i << 5);
            if (hw < HWN) {
                const float4* p4 = (const float4*)(xc + hw * QQ);
                float4 a = p4[0], d = p4[1];
                us[0] += a.x; us[1] += a.y; us[2] += a.z; us[3] += a.w;
                us[4] += d.x; us[5] += d.y; us[6] += d.z; us[7] += d.w;
            }
        }
#pragma unroll
        for (int m = 1; m <= 16; m <<= 1) {        // reduce over 32 slot lanes
#pragma unroll
            for (int q = 0; q < QQ; ++q) us[q] += __shfl_xor(us[q], m);
        }
        if (slot == 0) {
#pragma unroll
            for (int q = 0; q < QQ; ++q) usum_s[c * QQ + q] = us[q];
        }
    }
    __syncthreads();

    // heavy-phase thread map: 16 c x 16 slots x 2 oh
    const int hc    = tid >> 5;          // 0..15 local c
    const int hslot = (tid >> 1) & 15;   // 0..15
    const int oh    = tid & 1;           // 0..1
    const int obase = oh * OH;

    // ---- 3 phases: ph=0 -> v1 seed; ph=1,2 -> routing iters ----
    for (int ph = 0; ph < 3; ++ph) {
        // partial s[o,p] over own 16 c, split into 2 x 8-c halves (320 thr)
        if (tid < 2 * OO * PP) {
            const int h   = tid >= OO * PP;
            const int idx = h ? tid - OO * PP : tid;
            const int o = idx >> 4, p = idx & 15;
            const int c0 = h * 8;
            float s = 0.f;
#pragma unroll
            for (int k = 0; k < 8; ++k) {
                const int cc = c0 + k;
                const float4* w4 = (const float4*)(Wm_s + (((cc * OO + o) * PP + p) * QQ));
                float4 w0 = w4[0], w1 = w4[1];
                const float* src = (ph == 0) ? &usum_s[cc * QQ]
                                             : &t_s[(cc * OO + o) * QQ];
                s += w0.x * src[0] + w0.y * src[1] + w0.z * src[2] + w0.w * src[3]
                   + w1.x * src[4] + w1.y * src[5] + w1.z * src[6] + w1.w * src[7];
            }
            ps2_s[tid] = s;
        }
        __syncthreads();

        // ---- exchange 160-float s-partial with the partner block ----
        const int spin = (ph < 2) ? 1 : (ch == 0);
        float sown = 0.f;
        if (tid < OO * PP) {
            sown = ps2_s[tid] + ps2_s[OO * PP + tid];
            __hip_atomic_store(&g_sx[(((size_t)ph * BB + b) * 2 + ch) * (OO * PP) + tid],
                               sown, __ATOMIC_RELAXED, __HIP_MEMORY_SCOPE_AGENT);
        }
        __syncthreads();   // drains vmcnt(0): stores at the coherent point
        if (tid == 0) {
            unsigned t = __hip_atomic_fetch_add(&g_cnt[b * 32], 1u,
                             __ATOMIC_RELAXED, __HIP_MEMORY_SCOPE_AGENT);
            if (spin) {
                const unsigned target = (t / 2u + 1u) * 2u;
                while (__hip_atomic_load(&g_cnt[b * 32], __ATOMIC_RELAXED,
                                         __HIP_MEMORY_SCOPE_AGENT) < target)
                    __builtin_amdgcn_s_sleep(1);
            }
        }
        __syncthreads();
        if (!spin) return;   // ch1 at ph==2: posted, done

        // combine partials -> v (or final output)
        if (tid < OO * PP) {
            float soth = __hip_atomic_load(
                &g_sx[(((size_t)ph * BB + b) * 2 + (1 - ch)) * (OO * PP) + tid],
                __ATOMIC_RELAXED, __HIP_MEMORY_SCOPE_AGENT);
            float s = sown + soth;
            if (ph == 0) s *= 0.1f;          // iter-1 uniform c_ij
            const float v = squash16(s);
            if (ph == 2) { out[(size_t)b * (OO * PP) + tid] = v; }
            else         { v_s[tid] = v; }
        }
        if (ph == 2) return;
        __syncthreads();

        // ---- Wv (own c only; set on ph0, accumulate on ph1) ----
        if (tid < CL * OO) {
            const int cl = tid / OO, o = tid - cl * OO;
            float acc[QQ];
#pragma unroll
            for (int q = 0; q < QQ; ++q) acc[q] = 0.f;
            const float* wp = Wm_s + ((cl * OO + o) * PP) * QQ;
#pragma unroll
            for (int p = 0; p < PP; ++p) {
                const float vv = v_s[o * PP + p];
                const float4* w4 = (const float4*)(wp + p * QQ);
                float4 w0 = w4[0], w1 = w4[1];
                acc[0] += vv * w0.x; acc[1] += vv * w0.y; acc[2] += vv * w0.z; acc[3] += vv * w0.w;
                acc[4] += vv * w1.x; acc[5] += vv * w1.y; acc[6] += vv * w1.z; acc[7] += vv * w1.w;
            }
            float* dst = Wv_s + (cl * OO + o) * QQ;
            if (ph == 0) {
#pragma unroll
                for (int q = 0; q < QQ; ++q) dst[q] = acc[q];
            } else {
#pragma unroll
                for (int q = 0; q < QQ; ++q) dst[q] += acc[q];
            }
        }
        __syncthreads();

        // ---- heavy: u from LDS fp16; logits = u.Wv; defer-max softmax ----
        float wv[OH][QQ];
#pragma unroll
        for (int j = 0; j < OH; ++j)
#pragma unroll
            for (int q = 0; q < QQ; ++q)
                wv[j][q] = Wv_s[(hc * OO + obase + j) * QQ + q];

        float tl[OH][QQ];
#pragma unroll
        for (int j = 0; j < OH; ++j)
#pragma unroll
            for (int q = 0; q < QQ; ++q) tl[j][q] = 0.f;

#pragma unroll 3
        for (int i = 0; i < 9; ++i) {        // 144 = 16 slots * 9
            const int hw = hslot + (i << 4);
            // 16B LDS read: 8 fp16 = one (c,hw) input capsule
            float4 raw = *(const float4*)(x_s + (hc * HWN + hw) * QQ);
            const __half2* h2 = (const __half2*)&raw;
            float2 f0 = __half22float2(h2[0]);
            float2 f1 = __half22float2(h2[1]);
            float2 f2 = __half22float2(h2[2]);
            float2 f3 = __half22float2(h2[3]);
            float u[QQ] = {f0.x, f0.y, f1.x, f1.y, f2.x, f2.y, f3.x, f3.y};
            float lg[OH];
#pragma unroll
            for (int j = 0; j < OH; ++j) {
                float t = 0.f;
#pragma unroll
                for (int q = 0; q < QQ; ++q) t += u[q] * wv[j][q];
                lg[j] = __expf(t);           // defer-max: logits bounded, fp32-safe
            }
            float psum = ((lg[0] + lg[1]) + (lg[2] + lg[3])) + lg[4];
            psum += __shfl_xor(psum, 1);
            const float inv = 1.f / psum;
#pragma unroll
            for (int j = 0; j < OH; ++j) {
                const float cij = lg[j] * inv;
#pragma unroll
                for (int q = 0; q < QQ; ++q) tl[j][q] += cij * u[q];
            }
        }
        // reduce t over the 16 slot lanes (masks 2..16; oh is bit0)
#pragma unroll
        for (int m = 2; m <= 16; m <<= 1) {
#pragma unroll
            for (int j = 0; j < OH; ++j)
#pragma unroll
                for (int q = 0; q < QQ; ++q) tl[j][q] += __shfl_xor(tl[j][q], m);
        }
        if (hslot == 0) {
#pragma unroll
            for (int j = 0; j < OH; ++j)
#pragma unroll
                for (int q = 0; q < QQ; ++q)
                    t_s[(hc * OO + obase + j) * QQ + q] = tl[j][q];
        }
        __syncthreads();
    }
}

extern "C" void kernel_launch(void* const* d_in, const int* in_sizes, int n_in,
                              void* d_out, int out_size, void* d_ws, size_t ws_size,
                              hipStream_t stream) {
    const float* x  = (const float*)d_in[0];   // [128,32,12,12,8]
    const float* Wm = (const float*)d_in[1];   // [1,1,32,10,16,8]
    float* out      = (float*)d_out;           // [128,10,16]
    digitcaps_routing<<<dim3(BB, 2), 512, 0, stream>>>(x, Wm, out);
}